// Round 8
// baseline (616.057 us; speedup 1.0000x reference)
//
#include <hip/hip_runtime.h>
#include <math.h>

// Problem constants (match reference)
#define IN_DIM 128
#define HID 32
#define HEADS 8
#define OUT_DIM 16
#define NEG_SLOPE 0.2f

// ---------------------------------------------------------------------------
// CSR build: histogram of dst, exclusive scan, fill (src list grouped by dst)
// ---------------------------------------------------------------------------

__global__ void count_kernel(const int* __restrict__ ei, int* __restrict__ counts,
                             int E, int N) {
    int e = blockIdx.x * 256 + threadIdx.x;
    int Etot = E + N;
    if (e >= Etot) return;
    int dst = (e < E) ? ei[E + e] : (e - E);   // ei[E..2E) = dst row
    atomicAdd(&counts[dst], 1);
}

// Single-block scan over N counts -> off[0..N] (exclusive), pos = copy of off
__global__ __launch_bounds__(1024) void scan_kernel(const int* __restrict__ counts,
                                                    int* __restrict__ off,
                                                    int* __restrict__ pos, int N) {
    __shared__ int wsum[16];
    __shared__ int wbase[16];
    __shared__ int running_s;
    int tid = threadIdx.x;
    int lane = tid & 63, wid = tid >> 6;
    if (tid == 0) running_s = 0;
    __syncthreads();
    const int CH = 4096;   // 1024 threads x 4 elems
    int nchunk = (N + CH - 1) / CH;
    for (int c = 0; c < nchunk; ++c) {
        int base_i = c * CH + tid * 4;
        int v0 = (base_i + 0 < N) ? counts[base_i + 0] : 0;
        int v1 = (base_i + 1 < N) ? counts[base_i + 1] : 0;
        int v2 = (base_i + 2 < N) ? counts[base_i + 2] : 0;
        int v3 = (base_i + 3 < N) ? counts[base_i + 3] : 0;
        int tsum = v0 + v1 + v2 + v3;
        // inclusive wave scan of tsum
        int x = tsum;
        #pragma unroll
        for (int ofs = 1; ofs < 64; ofs <<= 1) {
            int y = __shfl_up(x, ofs, 64);
            if (lane >= ofs) x += y;
        }
        if (lane == 63) wsum[wid] = x;
        __syncthreads();
        if (wid == 0) {
            int w = (lane < 16) ? wsum[lane] : 0;
            #pragma unroll
            for (int ofs = 1; ofs < 64; ofs <<= 1) {
                int y = __shfl_up(w, ofs, 64);
                if (lane >= ofs) w += y;
            }
            if (lane < 16) wbase[lane] = w;   // inclusive scan of wave sums
        }
        __syncthreads();
        int chunk_base = running_s;
        int wave_excl = (wid == 0) ? 0 : wbase[wid - 1];
        int thr_excl = x - tsum;
        int b = chunk_base + wave_excl + thr_excl;
        if (base_i + 0 < N) { off[base_i + 0] = b; pos[base_i + 0] = b; } b += v0;
        if (base_i + 1 < N) { off[base_i + 1] = b; pos[base_i + 1] = b; } b += v1;
        if (base_i + 2 < N) { off[base_i + 2] = b; pos[base_i + 2] = b; } b += v2;
        if (base_i + 3 < N) { off[base_i + 3] = b; pos[base_i + 3] = b; }
        __syncthreads();
        if (tid == 0) running_s = chunk_base + wbase[15];
        __syncthreads();
    }
    if (tid == 0) off[N] = running_s;
}

__global__ void fill_kernel(const int* __restrict__ ei, int* __restrict__ pos,
                            int* __restrict__ csr_src, int E, int N) {
    int e = blockIdx.x * 256 + threadIdx.x;
    int Etot = E + N;
    if (e >= Etot) return;
    int src, dst;
    if (e < E) { src = ei[e]; dst = ei[E + e]; }
    else       { src = e - E; dst = e - E; }
    int idx = atomicAdd(&pos[dst], 1);
    csr_src[idx] = src;
}

// ---------------------------------------------------------------------------
// GEMM1 v2: hp1[N,256] = x[N,128] @ W1[128,256]   (fp32 vector ALU)
// tile 32 rows x 256 cols; thread = 8 rows x 4 cols (register tile).
// LDS b128 instructions per block drop 4x vs v1 (1024 vs 4096); W loads float4.
// ---------------------------------------------------------------------------
__global__ __launch_bounds__(256) void gemm1_kernel(const float* __restrict__ x,
                                                    const float* __restrict__ W,
                                                    float* __restrict__ hp, int N) {
    __shared__ float4 xs4[32 * 32];             // [row][k4], 16 KB
    int n0 = blockIdx.x * 32;
    int t = threadIdx.x;
    int rows = min(32, N - n0);
    const float4* xg = (const float4*)(x + (size_t)n0 * IN_DIM);
    int nf4 = rows * 32;
    for (int idx = t; idx < 1024; idx += 256)
        xs4[idx] = (idx < nf4) ? xg[idx] : make_float4(0.f, 0.f, 0.f, 0.f);
    __syncthreads();

    int c4 = t & 63;           // float4 column: output cols c4*4 .. c4*4+3
    int r0 = (t >> 6) * 8;     // rows r0 .. r0+7 (uniform per wave -> LDS broadcast)
    const float4* W4 = (const float4*)W;        // [128][64]
    float4 acc[8];
    #pragma unroll
    for (int i = 0; i < 8; ++i) acc[i] = make_float4(0.f, 0.f, 0.f, 0.f);

    #pragma unroll 4
    for (int k4 = 0; k4 < 32; ++k4) {
        float4 w0 = W4[(k4 * 4 + 0) * 64 + c4];
        float4 w1 = W4[(k4 * 4 + 1) * 64 + c4];
        float4 w2 = W4[(k4 * 4 + 2) * 64 + c4];
        float4 w3 = W4[(k4 * 4 + 3) * 64 + c4];
        #pragma unroll
        for (int i = 0; i < 8; ++i) {
            float4 xq = xs4[(r0 + i) * 32 + k4];   // broadcast within wave
            acc[i].x += xq.x * w0.x + xq.y * w1.x + xq.z * w2.x + xq.w * w3.x;
            acc[i].y += xq.x * w0.y + xq.y * w1.y + xq.z * w2.y + xq.w * w3.y;
            acc[i].z += xq.x * w0.z + xq.y * w1.z + xq.z * w2.z + xq.w * w3.z;
            acc[i].w += xq.x * w0.w + xq.y * w1.w + xq.z * w2.w + xq.w * w3.w;
        }
    }
    float4* hp4 = (float4*)hp;
    #pragma unroll
    for (int i = 0; i < 8; ++i)
        if (r0 + i < rows)
            hp4[(size_t)(n0 + r0 + i) * 64 + c4] = acc[i];
}

// ---------------------------------------------------------------------------
// alpha1: as1[n,h] = <hp1[n,h,:], a_src[h,:]>, ad1 likewise.  t = n*8+h
// ---------------------------------------------------------------------------
__global__ void alpha1_kernel(const float* __restrict__ hp,
                              const float* __restrict__ a_src,
                              const float* __restrict__ a_dst,
                              float* __restrict__ as, float* __restrict__ ad, int NH) {
    int t = blockIdx.x * 256 + threadIdx.x;
    if (t >= NH) return;
    int h = t & 7;
    const float4* hv  = (const float4*)(hp + (size_t)t * 32);
    const float4* av  = (const float4*)(a_src + h * 32);
    const float4* bv  = (const float4*)(a_dst + h * 32);
    float ss = 0.f, sd = 0.f;
    #pragma unroll
    for (int k = 0; k < 8; ++k) {
        float4 xv = hv[k], a = av[k], b = bv[k];
        ss += xv.x * a.x + xv.y * a.y + xv.z * a.z + xv.w * a.w;
        sd += xv.x * b.x + xv.y * b.y + xv.z * b.z + xv.w * b.w;
    }
    as[t] = ss;
    ad[t] = sd;
}

// ---------------------------------------------------------------------------
// Fused attention layer 1, v3: one block (256 thr) per dst node.
// Pass 1: per-head max (32 edge-slots x 8 heads, shfl_xor + LDS reduce).
// Pass 2 (FUSED): per 32-edge chunk compute unnormalized w = exp(e-m) once
//   into LDS, accumulate den_part per thread, and gather UNNORMALIZED
//   acc += w * hp[src]. Normalize by 1/den once at the end.
//   Gather base address via readfirstlane -> SALU address math.
// Removes the separate denominator pass (1/3 of edge work) vs v2.
// ---------------------------------------------------------------------------
__global__ __launch_bounds__(256) void attn1_kernel(const int* __restrict__ off,
                                                    const int* __restrict__ csr_src,
                                                    const float* __restrict__ as,
                                                    const float* __restrict__ ad,
                                                    const float* __restrict__ hp,
                                                    const float* __restrict__ bias,
                                                    float* __restrict__ out, int N) {
    __shared__ float sred[4][8];
    __shared__ float ws[32][8];
    __shared__ int   ss[32];
    __shared__ float sinv[8];
    int n = blockIdx.x;
    int t = threadIdx.x;
    int wid = t >> 6, lane = t & 63;
    int beg = off[n], end = off[n + 1];
    int h8 = t & 7;          // head (logit layout)
    int ie = t >> 3;         // edge slot 0..31
    float adn = ad[n * 8 + h8];

    // pass 1: per-head max
    float m = -INFINITY;
    for (int i = beg + ie; i < end; i += 32) {
        float e = as[csr_src[i] * 8 + h8] + adn;
        e = (e > 0.f) ? e : NEG_SLOPE * e;
        m = fmaxf(m, e);
    }
    m = fmaxf(m, __shfl_xor(m, 8, 64));
    m = fmaxf(m, __shfl_xor(m, 16, 64));
    m = fmaxf(m, __shfl_xor(m, 32, 64));
    if (lane < 8) sred[wid][lane] = m;
    __syncthreads();
    m = fmaxf(fmaxf(sred[0][h8], sred[1][h8]), fmaxf(sred[2][h8], sred[3][h8]));
    __syncthreads();

    // pass 2: fused denom + unnormalized gather
    int hh = t >> 5;                 // head for gather (t = hh*32 + d)
    float den_part = 0.f;
    float acc = 0.f;
    const float* hpt = hp + t;       // per-lane column base
    for (int c0 = beg; c0 < end; c0 += 32) {
        int i = c0 + ie;
        float w = 0.f; int s = 0;
        if (i < end) {
            s = csr_src[i];
            float e = as[s * 8 + h8] + adn;
            e = (e > 0.f) ? e : NEG_SLOPE * e;
            w = expf(e - m);
        }
        den_part += w;
        __syncthreads();             // protect ws/ss reuse across chunks
        ws[ie][h8] = w;
        if (h8 == 0) ss[ie] = s;
        __syncthreads();
        int cnt = min(32, end - c0);
        for (int j = 0; j < cnt; ++j) {
            int sj = __builtin_amdgcn_readfirstlane(ss[j]);   // uniform -> SGPR base
            acc += ws[j][hh] * hpt[(size_t)sj * 256];         // coalesced 1KB/edge
        }
    }
    // reduce den_part over edge slots (ie) for each head
    den_part += __shfl_xor(den_part, 8, 64);
    den_part += __shfl_xor(den_part, 16, 64);
    den_part += __shfl_xor(den_part, 32, 64);
    if (lane < 8) sred[wid][lane] = den_part;
    __syncthreads();
    if (t < 8) {
        float den = sred[0][t] + sred[1][t] + sred[2][t] + sred[3][t];
        sinv[t] = 1.f / (den + 1e-16f);
    }
    __syncthreads();
    float v = acc * sinv[hh] + bias[t];
    out[(size_t)n * 256 + t] = (v > 0.f) ? v : expm1f(v);
}

// ---------------------------------------------------------------------------
// GEMM2: hp2[N,32] = h1[N,256] @ W2[256,32]
// ---------------------------------------------------------------------------
__global__ __launch_bounds__(256) void gemm2_kernel(const float* __restrict__ h1,
                                                    const float* __restrict__ W2,
                                                    float* __restrict__ hp2, int N) {
    __shared__ float hs[8 * 256];               // 8 KB
    int n0 = blockIdx.x * 8;
    int t = threadIdx.x;
    int rows = min(8, N - n0);
    const float4* hg = (const float4*)(h1 + (size_t)n0 * 256);
    float4* hs4 = (float4*)hs;
    int nf4 = rows * 64;
    for (int idx = t; idx < 512; idx += 256)
        hs4[idx] = (idx < nf4) ? hg[idx] : make_float4(0.f, 0.f, 0.f, 0.f);
    __syncthreads();
    int i = t >> 5, j = t & 31;
    const float4* hrow = (const float4*)(hs + i * 256);
    float acc = 0.f;
    for (int k4 = 0; k4 < 64; ++k4) {
        float4 hv = hrow[k4];
        int k = k4 * 4;
        acc += hv.x * W2[(k + 0) * 32 + j] + hv.y * W2[(k + 1) * 32 + j]
             + hv.z * W2[(k + 2) * 32 + j] + hv.w * W2[(k + 3) * 32 + j];
    }
    if (i < rows) hp2[(size_t)(n0 + i) * 32 + j] = acc;
}

// alpha2: per node dot over 32 dims (heads = 1)
__global__ void alpha2_kernel(const float* __restrict__ hp2,
                              const float* __restrict__ a_src,
                              const float* __restrict__ a_dst,
                              float* __restrict__ as, float* __restrict__ ad, int N) {
    int t = blockIdx.x * 256 + threadIdx.x;
    if (t >= N) return;
    const float4* hv = (const float4*)(hp2 + (size_t)t * 32);
    const float4* av = (const float4*)a_src;
    const float4* bv = (const float4*)a_dst;
    float ss = 0.f, sd = 0.f;
    #pragma unroll
    for (int k = 0; k < 8; ++k) {
        float4 xv = hv[k], a = av[k], b = bv[k];
        ss += xv.x * a.x + xv.y * a.y + xv.z * a.z + xv.w * a.w;
        sd += xv.x * b.x + xv.y * b.y + xv.z * b.z + xv.w * b.w;
    }
    as[t] = ss;
    ad[t] = sd;
}

// ---------------------------------------------------------------------------
// Fused attention layer 2, v3 (H=1, D=32): 8 nodes/block, 32 lanes per node.
// Pass 1: max. Pass 2 (FUSED): unnormalized gather + den accumulation,
// normalize at the end. Saves one full edge pass vs v2.
// ---------------------------------------------------------------------------
__global__ __launch_bounds__(256) void attn2_kernel(const int* __restrict__ off,
                                                    const int* __restrict__ csr_src,
                                                    const float* __restrict__ as,
                                                    const float* __restrict__ ad,
                                                    const float* __restrict__ hp2,
                                                    const float* __restrict__ b2,
                                                    float* __restrict__ h2, int N) {
    int g = threadIdx.x >> 5, d = threadIdx.x & 31;
    int n = blockIdx.x * 8 + g;
    if (n >= N) return;
    int beg = off[n], end = off[n + 1];
    float adn = ad[n];

    float m = -INFINITY;
    for (int i = beg + d; i < end; i += 32) {
        float e = as[csr_src[i]] + adn;
        e = (e > 0.f) ? e : NEG_SLOPE * e;
        m = fmaxf(m, e);
    }
    #pragma unroll
    for (int mask = 16; mask >= 1; mask >>= 1) m = fmaxf(m, __shfl_xor(m, mask, 32));

    float den_part = 0.f;
    float acc = 0.f;
    for (int c0 = beg; c0 < end; c0 += 32) {
        int i = c0 + d;
        float w = 0.f; int s = 0;
        if (i < end) {
            s = csr_src[i];
            float e = as[s] + adn;
            e = (e > 0.f) ? e : NEG_SLOPE * e;
            w = expf(e - m);
        }
        den_part += w;
        int cnt = min(32, end - c0);
        for (int j = 0; j < cnt; ++j) {
            float wj = __shfl(w, j, 32);
            int   sj = __shfl(s, j, 32);
            acc += wj * hp2[(size_t)sj * 32 + d];
        }
    }
    #pragma unroll
    for (int mask = 16; mask >= 1; mask >>= 1) den_part += __shfl_xor(den_part, mask, 32);
    float inv = 1.f / (den_part + 1e-16f);

    float v = acc * inv + b2[d];
    h2[(size_t)n * 32 + d] = (v > 0.f) ? v : expm1f(v);
}

// Final linear: out[N,16] = h2[N,32] @ Wout[32,16] + bout
__global__ void out_kernel(const float* __restrict__ h2,
                           const float* __restrict__ Wout,
                           const float* __restrict__ bout,
                           float* __restrict__ out, int N) {
    int t = blockIdx.x * 256 + threadIdx.x;
    if (t >= N * OUT_DIM) return;
    int n = t >> 4, j = t & 15;
    const float* hr = h2 + (size_t)n * 32;
    float acc = bout[j];
    #pragma unroll
    for (int k = 0; k < 32; ++k)
        acc += hr[k] * Wout[k * OUT_DIM + j];
    out[t] = acc;
}

// ---------------------------------------------------------------------------

extern "C" void kernel_launch(void* const* d_in, const int* in_sizes, int n_in,
                              void* d_out, int out_size, void* d_ws, size_t ws_size,
                              hipStream_t stream) {
    const float* x      = (const float*)d_in[0];
    const int*   ei     = (const int*)d_in[1];
    const float* W1     = (const float*)d_in[2];
    const float* a_src1 = (const float*)d_in[3];
    const float* a_dst1 = (const float*)d_in[4];
    const float* b1     = (const float*)d_in[5];
    const float* W2     = (const float*)d_in[6];
    const float* a_src2 = (const float*)d_in[7];
    const float* a_dst2 = (const float*)d_in[8];
    const float* b2     = (const float*)d_in[9];
    const float* Wout   = (const float*)d_in[10];
    const float* bout   = (const float*)d_in[11];
    float* out = (float*)d_out;

    const int N = in_sizes[0] / IN_DIM;     // 50000
    const int E = in_sizes[1] / 2;          // 800000
    const int Etot = E + N;

    // workspace carve-up (256B aligned)
    char* p = (char*)d_ws;
    auto alloc = [&](size_t bytes) -> void* {
        void* r = (void*)p;
        p += (bytes + 255) & ~(size_t)255;
        return r;
    };
    float* hp1    = (float*)alloc((size_t)N * 256 * 4);
    float* h1     = (float*)alloc((size_t)N * 256 * 4);
    float* as1    = (float*)alloc((size_t)N * 8 * 4);
    float* ad1    = (float*)alloc((size_t)N * 8 * 4);
    float* hp2    = (float*)alloc((size_t)N * 32 * 4);
    float* as2    = (float*)alloc((size_t)N * 4);
    float* ad2    = (float*)alloc((size_t)N * 4);
    float* h2     = (float*)alloc((size_t)N * 32 * 4);
    int*   counts = (int*)alloc((size_t)N * 4);
    int*   off    = (int*)alloc((size_t)(N + 1) * 4);
    int*   pos    = (int*)alloc((size_t)N * 4);
    int*   csr    = (int*)alloc((size_t)Etot * 4);
    (void)ws_size;

    // --- CSR build ---
    hipMemsetAsync(counts, 0, (size_t)N * 4, stream);
    int eb = (Etot + 255) / 256;
    count_kernel<<<eb, 256, 0, stream>>>(ei, counts, E, N);
    scan_kernel<<<1, 1024, 0, stream>>>(counts, off, pos, N);
    fill_kernel<<<eb, 256, 0, stream>>>(ei, pos, csr, E, N);

    // --- layer 1 ---
    gemm1_kernel<<<(N + 31) / 32, 256, 0, stream>>>(x, W1, hp1, N);
    alpha1_kernel<<<(N * 8 + 255) / 256, 256, 0, stream>>>(hp1, a_src1, a_dst1, as1, ad1, N * 8);
    attn1_kernel<<<N, 256, 0, stream>>>(off, csr, as1, ad1, hp1, b1, h1, N);

    // --- layer 2 ---
    gemm2_kernel<<<(N + 7) / 8, 256, 0, stream>>>(h1, W2, hp2, N);
    alpha2_kernel<<<(N + 255) / 256, 256, 0, stream>>>(hp2, a_src2, a_dst2, as2, ad2, N);
    attn2_kernel<<<(N + 7) / 8, 256, 0, stream>>>(off, csr, as2, ad2, hp2, b2, h2, N);

    // --- output linear ---
    out_kernel<<<(N * OUT_DIM + 255) / 256, 256, 0, stream>>>(h2, Wout, bout, out, N);
}

// Round 14
// 527.340 us; speedup vs baseline: 1.1682x; 1.1682x over previous
//
#include <hip/hip_runtime.h>
#include <math.h>

// Problem constants (match reference)
#define IN_DIM 128
#define HID 32
#define HEADS 8
#define OUT_DIM 16
#define NEG_SLOPE 0.2f

// ---------------------------------------------------------------------------
// CSR build: histogram of dst, exclusive scan, fill (src list grouped by dst)
// ---------------------------------------------------------------------------

__global__ void count_kernel(const int* __restrict__ ei, int* __restrict__ counts,
                             int E, int N) {
    int e = blockIdx.x * 256 + threadIdx.x;
    int Etot = E + N;
    if (e >= Etot) return;
    int dst = (e < E) ? ei[E + e] : (e - E);   // ei[E..2E) = dst row
    atomicAdd(&counts[dst], 1);
}

// Single-block scan over N counts -> off[0..N] (exclusive), pos = copy of off
__global__ __launch_bounds__(1024) void scan_kernel(const int* __restrict__ counts,
                                                    int* __restrict__ off,
                                                    int* __restrict__ pos, int N) {
    __shared__ int wsum[16];
    __shared__ int wbase[16];
    __shared__ int running_s;
    int tid = threadIdx.x;
    int lane = tid & 63, wid = tid >> 6;
    if (tid == 0) running_s = 0;
    __syncthreads();
    const int CH = 4096;   // 1024 threads x 4 elems
    int nchunk = (N + CH - 1) / CH;
    for (int c = 0; c < nchunk; ++c) {
        int base_i = c * CH + tid * 4;
        int v0 = (base_i + 0 < N) ? counts[base_i + 0] : 0;
        int v1 = (base_i + 1 < N) ? counts[base_i + 1] : 0;
        int v2 = (base_i + 2 < N) ? counts[base_i + 2] : 0;
        int v3 = (base_i + 3 < N) ? counts[base_i + 3] : 0;
        int tsum = v0 + v1 + v2 + v3;
        // inclusive wave scan of tsum
        int x = tsum;
        #pragma unroll
        for (int ofs = 1; ofs < 64; ofs <<= 1) {
            int y = __shfl_up(x, ofs, 64);
            if (lane >= ofs) x += y;
        }
        if (lane == 63) wsum[wid] = x;
        __syncthreads();
        if (wid == 0) {
            int w = (lane < 16) ? wsum[lane] : 0;
            #pragma unroll
            for (int ofs = 1; ofs < 64; ofs <<= 1) {
                int y = __shfl_up(w, ofs, 64);
                if (lane >= ofs) w += y;
            }
            if (lane < 16) wbase[lane] = w;   // inclusive scan of wave sums
        }
        __syncthreads();
        int chunk_base = running_s;
        int wave_excl = (wid == 0) ? 0 : wbase[wid - 1];
        int thr_excl = x - tsum;
        int b = chunk_base + wave_excl + thr_excl;
        if (base_i + 0 < N) { off[base_i + 0] = b; pos[base_i + 0] = b; } b += v0;
        if (base_i + 1 < N) { off[base_i + 1] = b; pos[base_i + 1] = b; } b += v1;
        if (base_i + 2 < N) { off[base_i + 2] = b; pos[base_i + 2] = b; } b += v2;
        if (base_i + 3 < N) { off[base_i + 3] = b; pos[base_i + 3] = b; }
        __syncthreads();
        if (tid == 0) running_s = chunk_base + wbase[15];
        __syncthreads();
    }
    if (tid == 0) off[N] = running_s;
}

__global__ void fill_kernel(const int* __restrict__ ei, int* __restrict__ pos,
                            int* __restrict__ csr_src, int E, int N) {
    int e = blockIdx.x * 256 + threadIdx.x;
    int Etot = E + N;
    if (e >= Etot) return;
    int src, dst;
    if (e < E) { src = ei[e]; dst = ei[E + e]; }
    else       { src = e - E; dst = e - E; }
    int idx = atomicAdd(&pos[dst], 1);
    csr_src[idx] = src;
}

// ---------------------------------------------------------------------------
// GEMM1 v3: hp1[N,256] = x[N,128] @ W1[128,256], FUSED alpha1 epilogue.
// tile 32 rows x 256 cols; thread = 8 rows x 4 cols (register tile).
// Epilogue: as1[n,h] = <hp1[n,h,:], a_src1[h,:]> via 8-lane shfl reduce
// (head h = lane>>3 within each wave, q = lane&7 covers the 8 float4 of dim 32).
// Saves the separate alpha1 kernel's 51MB re-read of hp1.
// ---------------------------------------------------------------------------
__global__ __launch_bounds__(256) void gemm1_kernel(const float* __restrict__ x,
                                                    const float* __restrict__ W,
                                                    const float* __restrict__ a_src,
                                                    const float* __restrict__ a_dst,
                                                    float* __restrict__ hp,
                                                    float* __restrict__ as,
                                                    float* __restrict__ ad, int N) {
    __shared__ float4 xs4[32 * 32];             // [row][k4], 16 KB
    int n0 = blockIdx.x * 32;
    int t = threadIdx.x;
    int rows = min(32, N - n0);
    const float4* xg = (const float4*)(x + (size_t)n0 * IN_DIM);
    int nf4 = rows * 32;
    for (int idx = t; idx < 1024; idx += 256)
        xs4[idx] = (idx < nf4) ? xg[idx] : make_float4(0.f, 0.f, 0.f, 0.f);
    __syncthreads();

    int c4 = t & 63;           // float4 column: output cols c4*4 .. c4*4+3
    int r0 = (t >> 6) * 8;     // rows r0 .. r0+7 (uniform per wave -> LDS broadcast)
    const float4* W4 = (const float4*)W;        // [128][64]
    float4 acc[8];
    #pragma unroll
    for (int i = 0; i < 8; ++i) acc[i] = make_float4(0.f, 0.f, 0.f, 0.f);

    #pragma unroll 4
    for (int k4 = 0; k4 < 32; ++k4) {
        float4 w0 = W4[(k4 * 4 + 0) * 64 + c4];
        float4 w1 = W4[(k4 * 4 + 1) * 64 + c4];
        float4 w2 = W4[(k4 * 4 + 2) * 64 + c4];
        float4 w3 = W4[(k4 * 4 + 3) * 64 + c4];
        #pragma unroll
        for (int i = 0; i < 8; ++i) {
            float4 xq = xs4[(r0 + i) * 32 + k4];   // broadcast within wave
            acc[i].x += xq.x * w0.x + xq.y * w1.x + xq.z * w2.x + xq.w * w3.x;
            acc[i].y += xq.x * w0.y + xq.y * w1.y + xq.z * w2.y + xq.w * w3.y;
            acc[i].z += xq.x * w0.z + xq.y * w1.z + xq.z * w2.z + xq.w * w3.z;
            acc[i].w += xq.x * w0.w + xq.y * w1.w + xq.z * w2.w + xq.w * w3.w;
        }
    }
    float4* hp4 = (float4*)hp;
    #pragma unroll
    for (int i = 0; i < 8; ++i)
        if (r0 + i < rows)
            hp4[(size_t)(n0 + r0 + i) * 64 + c4] = acc[i];

    // fused alpha1: head h = c4>>3, q = c4&7 indexes the 8 float4s of dim 32
    int h = c4 >> 3, q = c4 & 7;
    float4 av = ((const float4*)a_src)[h * 8 + q];
    float4 bv = ((const float4*)a_dst)[h * 8 + q];
    #pragma unroll
    for (int i = 0; i < 8; ++i) {
        float ps = acc[i].x * av.x + acc[i].y * av.y + acc[i].z * av.z + acc[i].w * av.w;
        float pd = acc[i].x * bv.x + acc[i].y * bv.y + acc[i].z * bv.z + acc[i].w * bv.w;
        ps += __shfl_xor(ps, 1, 64); pd += __shfl_xor(pd, 1, 64);
        ps += __shfl_xor(ps, 2, 64); pd += __shfl_xor(pd, 2, 64);
        ps += __shfl_xor(ps, 4, 64); pd += __shfl_xor(pd, 4, 64);
        if (q == 0 && r0 + i < rows) {
            as[(size_t)(n0 + r0 + i) * 8 + h] = ps;
            ad[(size_t)(n0 + r0 + i) * 8 + h] = pd;
        }
    }
}

// ---------------------------------------------------------------------------
// Fused attention layer 1, v4: one block (256 thr) per dst node.
// Pass 1: per-head max (32 edge-slots x 8 heads, shfl_xor + LDS reduce).
// Pass 2 (FUSED): per 32-edge chunk compute unnormalized w = exp(e-m) once
//   into LDS, accumulate den_part per thread, and gather UNNORMALIZED
//   acc += w * hp[src] with plain VGPR addressing (v2 form — readfirstlane
//   serialized the loads and cost +72us in v3). Normalize once at the end.
// ---------------------------------------------------------------------------
__global__ __launch_bounds__(256) void attn1_kernel(const int* __restrict__ off,
                                                    const int* __restrict__ csr_src,
                                                    const float* __restrict__ as,
                                                    const float* __restrict__ ad,
                                                    const float* __restrict__ hp,
                                                    const float* __restrict__ bias,
                                                    float* __restrict__ out, int N) {
    __shared__ float sred[4][8];
    __shared__ float ws[32][8];
    __shared__ int   ss[32];
    __shared__ float sinv[8];
    int n = blockIdx.x;
    int t = threadIdx.x;
    int wid = t >> 6, lane = t & 63;
    int beg = off[n], end = off[n + 1];
    int h8 = t & 7;          // head (logit layout)
    int ie = t >> 3;         // edge slot 0..31
    float adn = ad[n * 8 + h8];

    // pass 1: per-head max
    float m = -INFINITY;
    for (int i = beg + ie; i < end; i += 32) {
        float e = as[csr_src[i] * 8 + h8] + adn;
        e = (e > 0.f) ? e : NEG_SLOPE * e;
        m = fmaxf(m, e);
    }
    m = fmaxf(m, __shfl_xor(m, 8, 64));
    m = fmaxf(m, __shfl_xor(m, 16, 64));
    m = fmaxf(m, __shfl_xor(m, 32, 64));
    if (lane < 8) sred[wid][lane] = m;
    __syncthreads();
    m = fmaxf(fmaxf(sred[0][h8], sred[1][h8]), fmaxf(sred[2][h8], sred[3][h8]));
    __syncthreads();

    // pass 2: fused denom + unnormalized gather (VGPR addressing)
    int hh = t >> 5;                 // head for gather (t = hh*32 + d)
    float den_part = 0.f;
    float acc = 0.f;
    for (int c0 = beg; c0 < end; c0 += 32) {
        int i = c0 + ie;
        float w = 0.f; int s = 0;
        if (i < end) {
            s = csr_src[i];
            float e = as[s * 8 + h8] + adn;
            e = (e > 0.f) ? e : NEG_SLOPE * e;
            w = expf(e - m);
        }
        den_part += w;
        __syncthreads();             // protect ws/ss reuse across chunks
        ws[ie][h8] = w;
        if (h8 == 0) ss[ie] = s;
        __syncthreads();
        int cnt = min(32, end - c0);
        for (int j = 0; j < cnt; ++j)
            acc += ws[j][hh] * hp[(size_t)ss[j] * 256 + t];   // coalesced 1KB/edge
    }
    // reduce den_part over edge slots (ie) for each head
    den_part += __shfl_xor(den_part, 8, 64);
    den_part += __shfl_xor(den_part, 16, 64);
    den_part += __shfl_xor(den_part, 32, 64);
    if (lane < 8) sred[wid][lane] = den_part;
    __syncthreads();
    if (t < 8) {
        float den = sred[0][t] + sred[1][t] + sred[2][t] + sred[3][t];
        sinv[t] = 1.f / (den + 1e-16f);
    }
    __syncthreads();
    float v = acc * sinv[hh] + bias[t];
    out[(size_t)n * 256 + t] = (v > 0.f) ? v : expm1f(v);
}

// ---------------------------------------------------------------------------
// GEMM2 v2: hp2[N,32] = h1[N,256] @ W2[256,32], FUSED alpha2 epilogue
// (32-lane shfl reduce per row; saves the alpha2 kernel).
// ---------------------------------------------------------------------------
__global__ __launch_bounds__(256) void gemm2_kernel(const float* __restrict__ h1,
                                                    const float* __restrict__ W2,
                                                    const float* __restrict__ a_src,
                                                    const float* __restrict__ a_dst,
                                                    float* __restrict__ hp2,
                                                    float* __restrict__ as,
                                                    float* __restrict__ ad, int N) {
    __shared__ float hs[8 * 256];               // 8 KB
    int n0 = blockIdx.x * 8;
    int t = threadIdx.x;
    int rows = min(8, N - n0);
    const float4* hg = (const float4*)(h1 + (size_t)n0 * 256);
    float4* hs4 = (float4*)hs;
    int nf4 = rows * 64;
    for (int idx = t; idx < 512; idx += 256)
        hs4[idx] = (idx < nf4) ? hg[idx] : make_float4(0.f, 0.f, 0.f, 0.f);
    __syncthreads();
    int i = t >> 5, j = t & 31;
    const float4* hrow = (const float4*)(hs + i * 256);
    float acc = 0.f;
    for (int k4 = 0; k4 < 64; ++k4) {
        float4 hv = hrow[k4];
        int k = k4 * 4;
        acc += hv.x * W2[(k + 0) * 32 + j] + hv.y * W2[(k + 1) * 32 + j]
             + hv.z * W2[(k + 2) * 32 + j] + hv.w * W2[(k + 3) * 32 + j];
    }
    if (i < rows) hp2[(size_t)(n0 + i) * 32 + j] = acc;

    // fused alpha2: reduce acc * a over the 32 lanes of this row
    float ps = acc * a_src[j];
    float pd = acc * a_dst[j];
    #pragma unroll
    for (int mask = 16; mask >= 1; mask >>= 1) {
        ps += __shfl_xor(ps, mask, 32);
        pd += __shfl_xor(pd, mask, 32);
    }
    if (j == 0 && i < rows) {
        as[n0 + i] = ps;
        ad[n0 + i] = pd;
    }
}

// ---------------------------------------------------------------------------
// Fused attention layer 2, v4 (H=1, D=32): 8 nodes/block, 32 lanes per node.
// Pass 1: max. Pass 2 (FUSED): unnormalized gather + den accumulation.
// Epilogue: ELU then FUSED output linear out[n,:16] = h2 @ Wout + bout
// via 32 __shfl broadcasts (saves h2 round-trip + out_kernel launch).
// ---------------------------------------------------------------------------
__global__ __launch_bounds__(256) void attn2_kernel(const int* __restrict__ off,
                                                    const int* __restrict__ csr_src,
                                                    const float* __restrict__ as,
                                                    const float* __restrict__ ad,
                                                    const float* __restrict__ hp2,
                                                    const float* __restrict__ b2,
                                                    const float* __restrict__ Wout,
                                                    const float* __restrict__ bout,
                                                    float* __restrict__ out, int N) {
    int g = threadIdx.x >> 5, d = threadIdx.x & 31;
    int n = blockIdx.x * 8 + g;
    if (n >= N) return;                 // whole 32-lane group exits together
    int beg = off[n], end = off[n + 1];
    float adn = ad[n];

    float m = -INFINITY;
    for (int i = beg + d; i < end; i += 32) {
        float e = as[csr_src[i]] + adn;
        e = (e > 0.f) ? e : NEG_SLOPE * e;
        m = fmaxf(m, e);
    }
    #pragma unroll
    for (int mask = 16; mask >= 1; mask >>= 1) m = fmaxf(m, __shfl_xor(m, mask, 32));

    float den_part = 0.f;
    float acc = 0.f;
    for (int c0 = beg; c0 < end; c0 += 32) {
        int i = c0 + d;
        float w = 0.f; int s = 0;
        if (i < end) {
            s = csr_src[i];
            float e = as[s] + adn;
            e = (e > 0.f) ? e : NEG_SLOPE * e;
            w = expf(e - m);
        }
        den_part += w;
        int cnt = min(32, end - c0);
        for (int j = 0; j < cnt; ++j) {
            float wj = __shfl(w, j, 32);
            int   sj = __shfl(s, j, 32);
            acc += wj * hp2[(size_t)sj * 32 + d];
        }
    }
    #pragma unroll
    for (int mask = 16; mask >= 1; mask >>= 1) den_part += __shfl_xor(den_part, mask, 32);
    float inv = 1.f / (den_part + 1e-16f);

    float v = acc * inv + b2[d];
    float h2d = (v > 0.f) ? v : expm1f(v);

    // fused output linear: out[n,j] = sum_k h2[k]*Wout[k,j] + bout[j]
    float o = 0.f;
    #pragma unroll
    for (int k = 0; k < 32; ++k) {
        float hk = __shfl(h2d, k, 32);
        if (d < 16) o += hk * Wout[k * OUT_DIM + d];
    }
    if (d < 16)
        out[(size_t)n * OUT_DIM + d] = o + bout[d];
}

// ---------------------------------------------------------------------------

extern "C" void kernel_launch(void* const* d_in, const int* in_sizes, int n_in,
                              void* d_out, int out_size, void* d_ws, size_t ws_size,
                              hipStream_t stream) {
    const float* x      = (const float*)d_in[0];
    const int*   ei     = (const int*)d_in[1];
    const float* W1     = (const float*)d_in[2];
    const float* a_src1 = (const float*)d_in[3];
    const float* a_dst1 = (const float*)d_in[4];
    const float* b1     = (const float*)d_in[5];
    const float* W2     = (const float*)d_in[6];
    const float* a_src2 = (const float*)d_in[7];
    const float* a_dst2 = (const float*)d_in[8];
    const float* b2     = (const float*)d_in[9];
    const float* Wout   = (const float*)d_in[10];
    const float* bout   = (const float*)d_in[11];
    float* out = (float*)d_out;

    const int N = in_sizes[0] / IN_DIM;     // 50000
    const int E = in_sizes[1] / 2;          // 800000
    const int Etot = E + N;

    // workspace carve-up (256B aligned)
    char* p = (char*)d_ws;
    auto alloc = [&](size_t bytes) -> void* {
        void* r = (void*)p;
        p += (bytes + 255) & ~(size_t)255;
        return r;
    };
    float* hp1    = (float*)alloc((size_t)N * 256 * 4);
    float* h1     = (float*)alloc((size_t)N * 256 * 4);
    float* as1    = (float*)alloc((size_t)N * 8 * 4);
    float* ad1    = (float*)alloc((size_t)N * 8 * 4);
    float* hp2    = (float*)alloc((size_t)N * 32 * 4);
    float* as2    = (float*)alloc((size_t)N * 4);
    float* ad2    = (float*)alloc((size_t)N * 4);
    int*   counts = (int*)alloc((size_t)N * 4);
    int*   off    = (int*)alloc((size_t)(N + 1) * 4);
    int*   pos    = (int*)alloc((size_t)N * 4);
    int*   csr    = (int*)alloc((size_t)Etot * 4);
    (void)ws_size;

    // --- CSR build ---
    hipMemsetAsync(counts, 0, (size_t)N * 4, stream);
    int eb = (Etot + 255) / 256;
    count_kernel<<<eb, 256, 0, stream>>>(ei, counts, E, N);
    scan_kernel<<<1, 1024, 0, stream>>>(counts, off, pos, N);
    fill_kernel<<<eb, 256, 0, stream>>>(ei, pos, csr, E, N);

    // --- layer 1 ---
    gemm1_kernel<<<(N + 31) / 32, 256, 0, stream>>>(x, W1, a_src1, a_dst1, hp1, as1, ad1, N);
    attn1_kernel<<<N, 256, 0, stream>>>(off, csr, as1, ad1, hp1, b1, h1, N);

    // --- layer 2 ---
    gemm2_kernel<<<(N + 7) / 8, 256, 0, stream>>>(h1, W2, a_src2, a_dst2, hp2, as2, ad2, N);
    attn2_kernel<<<(N + 7) / 8, 256, 0, stream>>>(off, csr, as2, ad2, hp2, b2, Wout, bout, out, N);
}